// Round 10
// baseline (940.189 us; speedup 1.0000x reference)
//
#include <hip/hip_runtime.h>
#include <hip/hip_cooperative_groups.h>

namespace cg = cooperative_groups;

#define N_NODES 50000
#define N_EDGES 800000
#define SCAN_BLOCKS 196          // ceil(50000/256)
#define WIN 6250                 // dst window per XCD group (50000/8)
#define GRID_ALL 782             // blocks in cooperative kernel (= L0/L1 tile count)

typedef __attribute__((ext_vector_type(8))) short short8;
typedef __attribute__((ext_vector_type(4))) float f32x4;
typedef unsigned short ushort_t;
typedef unsigned int uint_t;

// ---------------- helpers ----------------
__device__ inline ushort_t f2bf(float f) {
    union { float f; uint_t u; } v; v.f = f;
    uint_t u = v.u;
    u += 0x7fffu + ((u >> 16) & 1u);   // RNE
    return (ushort_t)(u >> 16);
}
__device__ inline float bflo(uint_t v) { return __uint_as_float(v << 16); }
__device__ inline float bfhi(uint_t v) { return __uint_as_float(v & 0xffff0000u); }

#define ACC8(V) { a[0] += bflo((V).x); a[1] += bfhi((V).x); \
                  a[2] += bflo((V).y); a[3] += bfhi((V).y); \
                  a[4] += bflo((V).z); a[5] += bfhi((V).z); \
                  a[6] += bflo((V).w); a[7] += bfhi((V).w); }

// ---------------- shared device phases ----------------
// fused layer phase: mean-aggregate (wide gather) -> LDS -> MFMA GEMM
// (-> optional 2nd GEMM for the layer-2 transform). Proven 46.6us structure.
template <bool ZR>
__device__ __forceinline__ void layer_phase(
    uint_t (*mlds)[68],
    const ushort_t* __restrict__ feat_bf,
    const int* __restrict__ rowstart,
    const int* __restrict__ csr_src,
    const ushort_t* __restrict__ Bpk, const float* __restrict__ bias,
    const ushort_t* __restrict__ Bz, const float* __restrict__ bias2,
    ushort_t* __restrict__ out_bf,
    ushort_t* __restrict__ z_bf, float* __restrict__ r_f32) {
    int lane = threadIdx.x & 63;
    int wave = threadIdx.x >> 6;
    int rowBase = blockIdx.x * 64 + wave * 16;
    int sub = lane >> 4;                  // node slot within wave pass
    int sl  = lane & 15;                  // lane within node row
    int gb  = sub << 4;
    const uint_t* base = (const uint_t*)feat_bf;

    for (int p = 0; p < 4; ++p) {
        int node = rowBase + p * 4 + sub;
        int s0 = 0, s1 = 0;
        if (node < N_NODES) { s0 = rowstart[node]; s1 = rowstart[node + 1]; }
        float a[8];
        #pragma unroll
        for (int k = 0; k < 8; ++k) a[k] = 0.f;

        int pos = s0;
        while (__any(pos < s1)) {
            int m = min(16, s1 - pos);               // group-uniform, may be <=0
            int idxr = (sl < m) ? csr_src[pos + sl] : 0;
            int mm = max(m, 0);
            mm = max(mm, __shfl_xor(mm, 16, 64));
            mm = max(mm, __shfl_xor(mm, 32, 64));
            for (int j = 0; j < mm; j += 8) {
                int  sidx[8];
                bool vld[8];
                #pragma unroll
                for (int k = 0; k < 8; ++k) {
                    int q = __shfl(idxr, (gb + j + k) & 63, 64);
                    vld[k]  = (j + k < m);
                    sidx[k] = vld[k] ? q : 0;        // safe clamped addr, result discarded
                }
                uint4 V[8];
                #pragma unroll
                for (int k = 0; k < 8; ++k)
                    V[k] = *(const uint4*)(base + (size_t)sidx[k] * 64 + (sl << 2));
                #pragma unroll
                for (int k = 0; k < 8; ++k)
                    if (vld[k]) { ACC8(V[k]); }
            }
            pos += 16;
        }
        float inv = 1.0f / fmaxf((float)(s1 - s0), 1.0f);
        uint4 o;
        o.x = (uint_t)f2bf(a[0] * inv) | ((uint_t)f2bf(a[1] * inv) << 16);
        o.y = (uint_t)f2bf(a[2] * inv) | ((uint_t)f2bf(a[3] * inv) << 16);
        o.z = (uint_t)f2bf(a[4] * inv) | ((uint_t)f2bf(a[5] * inv) << 16);
        o.w = (uint_t)f2bf(a[6] * inv) | ((uint_t)f2bf(a[7] * inv) << 16);
        *((uint4*)&mlds[wave * 16 + p * 4 + sub][sl << 2]) = o;
    }
    __syncthreads();

    // ---- GEMM-1: A = [mean(LDS) | root(global)], B pre-packed ----
    int row16 = lane & 15;
    int quad  = lane >> 4;
    int arow  = min(rowBase + row16, N_NODES - 1);
    const ushort_t* rrow = feat_bf + (size_t)arow * 128;
    const short8* bp = (const short8*)Bpk + lane;

    f32x4 acc[8];
    #pragma unroll
    for (int t = 0; t < 8; ++t) { f32x4 z = {0.f, 0.f, 0.f, 0.f}; acc[t] = z; }

    #pragma unroll
    for (int ks = 0; ks < 8; ++ks) {
        short8 afrag;
        if (ks < 4)
            afrag = *(const short8*)&mlds[wave * 16 + row16][ks * 16 + quad * 4];
        else
            afrag = *(const short8*)(rrow + (ks - 4) * 32 + quad * 8);
        #pragma unroll
        for (int t = 0; t < 8; ++t) {
            short8 bfrag = bp[(ks * 8 + t) * 64];
            acc[t] = __builtin_amdgcn_mfma_f32_16x16x32_bf16(afrag, bfrag, acc[t], 0, 0, 0);
        }
    }

    if (!ZR) {
        #pragma unroll
        for (int t = 0; t < 8; ++t) {
            int col = t * 16 + row16;
            float bv = bias[col];
            #pragma unroll
            for (int r = 0; r < 4; ++r) {
                int row = rowBase + quad * 4 + r;
                if (row < N_NODES) {
                    float v = fmaxf(acc[t][r] + bv, 0.f);
                    out_bf[(size_t)row * 128 + col] = f2bf(v);
                }
            }
        }
    } else {
        // h2 tile -> LDS (reuse mean tile; wave-local, mean already consumed)
        #pragma unroll
        for (int t = 0; t < 8; ++t) {
            int col = t * 16 + row16;
            float bv = bias[col];
            #pragma unroll
            for (int r = 0; r < 4; ++r) {
                float v = fmaxf(acc[t][r] + bv, 0.f);
                ((ushort_t*)&mlds[wave * 16 + quad * 4 + r][0])[col] = f2bf(v);
            }
        }
        __syncthreads();

        // ---- GEMM-2: [z | r] = h2(LDS) @ [Wl2 | Wr2] ----
        const short8* bz = (const short8*)Bz + lane;
        f32x4 acc2[8];
        #pragma unroll
        for (int t = 0; t < 8; ++t) { f32x4 z = {0.f, 0.f, 0.f, 0.f}; acc2[t] = z; }

        #pragma unroll
        for (int ks = 0; ks < 4; ++ks) {
            short8 afrag = *(const short8*)((const ushort_t*)&mlds[wave * 16 + row16][0]
                                            + ks * 32 + quad * 8);
            #pragma unroll
            for (int t = 0; t < 8; ++t) {
                short8 bfrag = bz[(ks * 8 + t) * 64];
                acc2[t] = __builtin_amdgcn_mfma_f32_16x16x32_bf16(afrag, bfrag, acc2[t], 0, 0, 0);
            }
        }

        #pragma unroll
        for (int t = 0; t < 8; ++t) {
            int col = t * 16 + row16;
            #pragma unroll
            for (int r = 0; r < 4; ++r) {
                int row = rowBase + quad * 4 + r;
                if (row < N_NODES) {
                    if (col < 64) {
                        z_bf[(size_t)row * 64 + col] = f2bf(acc2[t][r]);
                    } else {
                        r_f32[(size_t)row * 64 + (col - 64)] = acc2[t][r] + bias2[col - 64];
                    }
                }
            }
        }
    }
}

// final phase body for one 32-node virtual block vb
__device__ __forceinline__ void final_phase_vb(
    int vb,
    const ushort_t* __restrict__ z_bf, const float* __restrict__ r_f32,
    const int* __restrict__ rowstart, const int* __restrict__ csr_src,
    float* __restrict__ out) {
    int lane = threadIdx.x & 63;
    int wave = threadIdx.x >> 6;
    int sub = lane >> 3;                  // node slot 0..7
    int sl  = lane & 7;                   // lane within node row
    int gb  = sub << 3;
    int node = vb * 32 + wave * 8 + sub;
    int s0 = 0, s1 = 0;
    if (node < N_NODES) { s0 = rowstart[node]; s1 = rowstart[node + 1]; }

    float a[8];
    #pragma unroll
    for (int k = 0; k < 8; ++k) a[k] = 0.f;
    const uint_t* zb = (const uint_t*)z_bf;

    int pos = s0;
    while (__any(pos < s1)) {
        int m = min(8, s1 - pos);
        int idxr = (sl < m) ? csr_src[pos + sl] : 0;
        int  sidx[8];
        bool vld[8];
        #pragma unroll
        for (int k = 0; k < 8; ++k) {
            int q = __shfl(idxr, (gb + k) & 63, 64);
            vld[k]  = (k < m);
            sidx[k] = vld[k] ? q : 0;
        }
        uint4 V[8];
        #pragma unroll
        for (int k = 0; k < 8; ++k)
            V[k] = *(const uint4*)(zb + (size_t)sidx[k] * 32 + (sl << 2));
        #pragma unroll
        for (int k = 0; k < 8; ++k)
            if (vld[k]) { ACC8(V[k]); }
        pos += 8;
    }
    if (node >= N_NODES) return;   // safe: no block-level sync after this phase

    float inv = 1.0f / fmaxf((float)(s1 - s0), 1.0f);
    const float4* rr = (const float4*)(r_f32 + (size_t)node * 64 + sl * 8);
    float4 rA = rr[0], rB = rr[1];
    float h[8];
    h[0] = a[0] * inv + rA.x; h[1] = a[1] * inv + rA.y;
    h[2] = a[2] * inv + rA.z; h[3] = a[3] * inv + rA.w;
    h[4] = a[4] * inv + rB.x; h[5] = a[5] * inv + rB.y;
    h[6] = a[6] * inv + rB.z; h[7] = a[7] * inv + rB.w;

    float mx = fmaxf(fmaxf(fmaxf(h[0], h[1]), fmaxf(h[2], h[3])),
                     fmaxf(fmaxf(h[4], h[5]), fmaxf(h[6], h[7])));
    mx = fmaxf(mx, __shfl_xor(mx, 1, 64));
    mx = fmaxf(mx, __shfl_xor(mx, 2, 64));
    mx = fmaxf(mx, __shfl_xor(mx, 4, 64));
    float s = 0.f;
    #pragma unroll
    for (int k = 0; k < 8; ++k) s += expf(h[k] - mx);
    s += __shfl_xor(s, 1, 64);
    s += __shfl_xor(s, 2, 64);
    s += __shfl_xor(s, 4, 64);
    float lse = mx + logf(s);

    size_t o1 = (size_t)node * 64 + sl * 8;
    size_t o2 = (size_t)N_NODES * 64 + o1;
    *(float4*)(out + o1)     = make_float4(h[0] - lse, h[1] - lse, h[2] - lse, h[3] - lse);
    *(float4*)(out + o1 + 4) = make_float4(h[4] - lse, h[5] - lse, h[6] - lse, h[7] - lse);
    *(float4*)(out + o2)     = make_float4(h[0], h[1], h[2], h[3]);
    *(float4*)(out + o2 + 4) = make_float4(h[4], h[5], h[6], h[7]);
}

// ---------------- THE cooperative mega-kernel: whole pipeline, 1 dispatch ----------------
// 7 grid.sync()s replace 7 dispatch boundaries (~8-10us each in this harness).
__global__ __launch_bounds__(256, 4) void sage_all(
    const float* __restrict__ x, const int* __restrict__ ei,
    const float* __restrict__ Wl0, const float* __restrict__ Wr0, const float* __restrict__ b0,
    const float* __restrict__ Wl1, const float* __restrict__ Wr1, const float* __restrict__ b1,
    const float* __restrict__ Wl2, const float* __restrict__ Wr2, const float* __restrict__ b2,
    int* __restrict__ cnt, int* __restrict__ rowstart, int* __restrict__ cursor,
    int* __restrict__ bsum, int* __restrict__ csr_src,
    ushort_t* __restrict__ pk0, ushort_t* __restrict__ pk1, ushort_t* __restrict__ pkz,
    ushort_t* __restrict__ x_bf, ushort_t* __restrict__ h_bf,
    ushort_t* __restrict__ z_bf, float* __restrict__ r_f32,
    float* __restrict__ out) {
    cg::grid_group grid = cg::this_grid();
    __shared__ uint_t mlds[64][68];
    __shared__ int ssc[256];
    __shared__ int psc[256];
    __shared__ int s4[4];

    const int tid = blockIdx.x * 256 + threadIdx.x;
    const int nthr = gridDim.x * 256;

    // ---- P0: zero cnt + x->bf16 + weight packs ----
    for (int i = tid; i < N_NODES; i += nthr) cnt[i] = 0;
    for (int i = tid; i < 1600000; i += nthr) {
        float4 v = ((const float4*)x)[i];
        ushort4 o;
        o.x = f2bf(v.x); o.y = f2bf(v.y); o.z = f2bf(v.z); o.w = f2bf(v.w);
        ((ushort4*)x_bf)[i] = o;
    }
    for (int gi = tid; gi < 81920; gi += nthr) {
        const float* Wl; const float* Wr; ushort_t* dst; int idx; bool zr = false;
        if (gi < 32768)      { Wl = Wl0; Wr = Wr0; dst = pk0; idx = gi; }
        else if (gi < 65536) { Wl = Wl1; Wr = Wr1; dst = pk1; idx = gi - 32768; }
        else                 { Wl = Wl2; Wr = Wr2; dst = pkz; idx = gi - 65536; zr = true; }
        int j = idx & 7, l = (idx >> 3) & 63, t = (idx >> 9) & 7, ks = idx >> 12;
        int n = t * 16 + (l & 15);
        int k = ks * 32 + (l >> 4) * 8 + j;
        float w;
        if (zr) w = (n < 64) ? Wl[k * 64 + n] : Wr[k * 64 + (n - 64)];
        else    w = (k < 128) ? Wl[k * 128 + n] : Wr[(k - 128) * 128 + n];
        dst[idx] = f2bf(w);
    }
    grid.sync();

    // ---- P1: XCD-windowed edge counting (int4 reads) ----
    {
        int role = blockIdx.x & 7, bi = blockIdx.x >> 3;
        int nbr = (gridDim.x + 7 - role) >> 3;
        int lo = role * WIN;
        const int4* dv = (const int4*)(ei + N_EDGES);
        for (int q = bi * 256 + threadIdx.x; q < N_EDGES / 4; q += nbr * 256) {
            int4 d = dv[q];
            if ((unsigned)(d.x - lo) < WIN) atomicAdd(&cnt[d.x], 1);
            if ((unsigned)(d.y - lo) < WIN) atomicAdd(&cnt[d.y], 1);
            if ((unsigned)(d.z - lo) < WIN) atomicAdd(&cnt[d.z], 1);
            if ((unsigned)(d.w - lo) < WIN) atomicAdd(&cnt[d.w], 1);
        }
    }
    grid.sync();

    // ---- P2: per-chunk block sums ----
    if (blockIdx.x < SCAN_BLOCKS) {
        int i = blockIdx.x * 256 + threadIdx.x;
        int v = (i < N_NODES) ? cnt[i] : 0;
        for (int off = 32; off; off >>= 1) v += __shfl_down(v, off, 64);
        if ((threadIdx.x & 63) == 0) s4[threadIdx.x >> 6] = v;
        __syncthreads();
        if (threadIdx.x == 0) bsum[blockIdx.x] = s4[0] + s4[1] + s4[2] + s4[3];
    }
    grid.sync();

    // ---- P3: merged scan (chunk scan + bsum scan) -> rowstart/cursor ----
    if (blockIdx.x < SCAN_BLOCKS) {
        int t = threadIdx.x;
        int i = blockIdx.x * 256 + t;
        int v = (i < N_NODES) ? cnt[i] : 0;
        int bv = (t < SCAN_BLOCKS) ? bsum[t] : 0;
        ssc[t] = v;
        psc[t] = bv;
        __syncthreads();
        for (int off = 1; off < 256; off <<= 1) {
            int as_ = (t >= off) ? ssc[t - off] : 0;
            int ap_ = (t >= off) ? psc[t - off] : 0;
            __syncthreads();
            ssc[t] += as_;
            psc[t] += ap_;
            __syncthreads();
        }
        int bprefix = (blockIdx.x > 0) ? psc[blockIdx.x - 1] : 0;
        int excl = ssc[t] - v + bprefix;
        if (i < N_NODES) { rowstart[i] = excl; cursor[i] = excl; }
        if (blockIdx.x == 0 && t == 0) rowstart[N_NODES] = N_EDGES;
    }
    grid.sync();

    // ---- P4: CSR fill (int4 reads) ----
    {
        int role = blockIdx.x & 7, bi = blockIdx.x >> 3;
        int nbr = (gridDim.x + 7 - role) >> 3;
        int lo = role * WIN;
        const int4* dv = (const int4*)(ei + N_EDGES);
        const int4* sv = (const int4*)ei;
        for (int q = bi * 256 + threadIdx.x; q < N_EDGES / 4; q += nbr * 256) {
            int4 d = dv[q];
            bool m0 = (unsigned)(d.x - lo) < WIN;
            bool m1 = (unsigned)(d.y - lo) < WIN;
            bool m2 = (unsigned)(d.z - lo) < WIN;
            bool m3 = (unsigned)(d.w - lo) < WIN;
            if (m0 | m1 | m2 | m3) {
                int4 s = sv[q];
                if (m0) { int p = atomicAdd(&cursor[d.x], 1); csr_src[p] = s.x; }
                if (m1) { int p = atomicAdd(&cursor[d.y], 1); csr_src[p] = s.y; }
                if (m2) { int p = atomicAdd(&cursor[d.z], 1); csr_src[p] = s.z; }
                if (m3) { int p = atomicAdd(&cursor[d.w], 1); csr_src[p] = s.w; }
            }
        }
    }
    grid.sync();

    // ---- P5: layer 0 fused (x_bf -> h_bf) ----
    layer_phase<false>(mlds, x_bf, rowstart, csr_src, pk0, b0,
                       nullptr, nullptr, h_bf, nullptr, nullptr);
    grid.sync();

    // ---- P6: layer 1 fused + layer-2 transform (h_bf -> z_bf, r_f32) ----
    layer_phase<true>(mlds, h_bf, rowstart, csr_src, pk1, b1,
                      pkz, b2, nullptr, z_bf, r_f32);
    grid.sync();

    // ---- P7: final gather + residual + log_softmax ----
    for (int vb = blockIdx.x; vb < 1563; vb += gridDim.x)
        final_phase_vb(vb, z_bf, r_f32, rowstart, csr_src, out);
}

// =================== classic fallback path (R9 pipeline) ===================
__global__ void prep(const int* __restrict__ ei, int* __restrict__ cnt,
                     const float* __restrict__ x, ushort_t* __restrict__ x_bf,
                     const float* __restrict__ Wl0, const float* __restrict__ Wr0,
                     const float* __restrict__ Wl1, const float* __restrict__ Wr1,
                     const float* __restrict__ Wl2, const float* __restrict__ Wr2,
                     ushort_t* __restrict__ pk0, ushort_t* __restrict__ pk1,
                     ushort_t* __restrict__ pkz) {
    int b = blockIdx.x;
    if (b < 1024) {
        int g = b & 7;
        int bi = b >> 3;
        int lo = g * WIN;
        const int4* dv = (const int4*)(ei + N_EDGES);
        for (int q = bi * 256 + threadIdx.x; q < N_EDGES / 4; q += 128 * 256) {
            int4 d = dv[q];
            if ((unsigned)(d.x - lo) < WIN) atomicAdd(&cnt[d.x], 1);
            if ((unsigned)(d.y - lo) < WIN) atomicAdd(&cnt[d.y], 1);
            if ((unsigned)(d.z - lo) < WIN) atomicAdd(&cnt[d.z], 1);
            if ((unsigned)(d.w - lo) < WIN) atomicAdd(&cnt[d.w], 1);
        }
    } else if (b < 7274) {
        int i = (b - 1024) * 256 + threadIdx.x;
        if (i < 1600000) {
            float4 v = ((const float4*)x)[i];
            ushort4 o;
            o.x = f2bf(v.x); o.y = f2bf(v.y); o.z = f2bf(v.z); o.w = f2bf(v.w);
            ((ushort4*)x_bf)[i] = o;
        }
    } else {
        int gi = (b - 7274) * 256 + threadIdx.x;
        const float* Wl; const float* Wr; ushort_t* dst; int idx; bool zr = false;
        if (gi < 32768)       { Wl = Wl0; Wr = Wr0; dst = pk0; idx = gi; }
        else if (gi < 65536)  { Wl = Wl1; Wr = Wr1; dst = pk1; idx = gi - 32768; }
        else if (gi < 81920)  { Wl = Wl2; Wr = Wr2; dst = pkz; idx = gi - 65536; zr = true; }
        else return;
        int j = idx & 7, l = (idx >> 3) & 63, t = (idx >> 9) & 7, ks = idx >> 12;
        int n = t * 16 + (l & 15);
        int k = ks * 32 + (l >> 4) * 8 + j;
        float w;
        if (zr) w = (n < 64) ? Wl[k * 64 + n] : Wr[k * 64 + (n - 64)];
        else    w = (k < 128) ? Wl[k * 128 + n] : Wr[(k - 128) * 128 + n];
        dst[idx] = f2bf(w);
    }
}

__global__ void fill_csr_mp(const int* __restrict__ ei, int* __restrict__ cursor,
                            int* __restrict__ csr_src) {
    int g = blockIdx.x & 7;
    int nb = gridDim.x >> 3;
    int bi = blockIdx.x >> 3;
    int lo = g * WIN;
    const int4* dv = (const int4*)(ei + N_EDGES);
    const int4* sv = (const int4*)ei;
    for (int q = bi * 256 + threadIdx.x; q < N_EDGES / 4; q += nb * 256) {
        int4 d = dv[q];
        bool m0 = (unsigned)(d.x - lo) < WIN;
        bool m1 = (unsigned)(d.y - lo) < WIN;
        bool m2 = (unsigned)(d.z - lo) < WIN;
        bool m3 = (unsigned)(d.w - lo) < WIN;
        if (m0 | m1 | m2 | m3) {
            int4 s = sv[q];
            if (m0) { int p = atomicAdd(&cursor[d.x], 1); csr_src[p] = s.x; }
            if (m1) { int p = atomicAdd(&cursor[d.y], 1); csr_src[p] = s.y; }
            if (m2) { int p = atomicAdd(&cursor[d.z], 1); csr_src[p] = s.z; }
            if (m3) { int p = atomicAdd(&cursor[d.w], 1); csr_src[p] = s.w; }
        }
    }
}

__global__ void block_sums(const int* __restrict__ cnt, int* __restrict__ bsum) {
    int i = blockIdx.x * 256 + threadIdx.x;
    int v = (i < N_NODES) ? cnt[i] : 0;
    for (int off = 32; off; off >>= 1) v += __shfl_down(v, off, 64);
    __shared__ int s[4];
    if ((threadIdx.x & 63) == 0) s[threadIdx.x >> 6] = v;
    __syncthreads();
    if (threadIdx.x == 0) bsum[blockIdx.x] = s[0] + s[1] + s[2] + s[3];
}

__global__ void apply_scan2(const int* __restrict__ cnt, const int* __restrict__ bsum,
                            int* __restrict__ rowstart, int* __restrict__ cursor) {
    __shared__ int s[256];
    __shared__ int p[256];
    int t = threadIdx.x;
    int i = blockIdx.x * 256 + t;
    int v = (i < N_NODES) ? cnt[i] : 0;
    int bv = (t < SCAN_BLOCKS) ? bsum[t] : 0;
    s[t] = v;
    p[t] = bv;
    __syncthreads();
    for (int off = 1; off < 256; off <<= 1) {
        int as_ = (t >= off) ? s[t - off] : 0;
        int ap_ = (t >= off) ? p[t - off] : 0;
        __syncthreads();
        s[t] += as_;
        p[t] += ap_;
        __syncthreads();
    }
    int bprefix = (blockIdx.x > 0) ? p[blockIdx.x - 1] : 0;
    int excl = s[t] - v + bprefix;
    if (i < N_NODES) { rowstart[i] = excl; cursor[i] = excl; }
    if (blockIdx.x == 0 && t == 0) rowstart[N_NODES] = N_EDGES;
}

template <bool ZR>
__global__ __launch_bounds__(256) void sage_fused_k(
    const ushort_t* __restrict__ feat_bf,
    const int* __restrict__ rowstart,
    const int* __restrict__ csr_src,
    const ushort_t* __restrict__ Bpk, const float* __restrict__ bias,
    const ushort_t* __restrict__ Bz, const float* __restrict__ bias2,
    ushort_t* __restrict__ out_bf,
    ushort_t* __restrict__ z_bf, float* __restrict__ r_f32) {
    __shared__ uint_t mlds[64][68];
    layer_phase<ZR>(mlds, feat_bf, rowstart, csr_src, Bpk, bias, Bz, bias2,
                    out_bf, z_bf, r_f32);
}

__global__ __launch_bounds__(256) void final_agg_softmax2(
    const ushort_t* __restrict__ z_bf, const float* __restrict__ r_f32,
    const int* __restrict__ rowstart, const int* __restrict__ csr_src,
    float* __restrict__ out) {
    final_phase_vb(blockIdx.x, z_bf, r_f32, rowstart, csr_src, out);
}

extern "C" void kernel_launch(void* const* d_in, const int* in_sizes, int n_in,
                              void* d_out, int out_size, void* d_ws, size_t ws_size,
                              hipStream_t stream) {
    const float* x  = (const float*)d_in[0];
    const int* ei   = (const int*)d_in[1];
    const float* Wl0 = (const float*)d_in[2];
    const float* Wr0 = (const float*)d_in[3];
    const float* b0  = (const float*)d_in[4];
    const float* Wl1 = (const float*)d_in[5];
    const float* Wr1 = (const float*)d_in[6];
    const float* b1  = (const float*)d_in[7];
    const float* Wl2 = (const float*)d_in[8];
    const float* Wr2 = (const float*)d_in[9];
    const float* b2  = (const float*)d_in[10];
    float* out = (float*)d_out;

    char* ws = (char*)d_ws;
    int* cnt      = (int*)(ws + 0x000000);
    int* rowstart = (int*)(ws + 0x040000);
    int* cursor   = (int*)(ws + 0x080000);
    int* bsum     = (int*)(ws + 0x0C0000);
    int* csr_src  = (int*)(ws + 0x100000);            // 3.2 MB
    ushort_t* pk0 = (ushort_t*)(ws + 0x420000);       // 64 KB
    ushort_t* pk1 = (ushort_t*)(ws + 0x440000);       // 64 KB
    ushort_t* pkz = (ushort_t*)(ws + 0x460000);       // 32 KB
    ushort_t* x_bf = (ushort_t*)(ws + 0x0500000);     // 12.8 MB [50000][128]
    ushort_t* h_bf = (ushort_t*)(ws + 0x1200000);     // 12.8 MB [50000][128]
    ushort_t* z_bf = (ushort_t*)(ws + 0x1F00000);     // 6.4 MB  [50000][64]
    float*    r_f32 = (float*)  (ws + 0x2600000);     // 12.8 MB [50000][64]

    // ---- preferred: single cooperative dispatch ----
    void* kargs[] = {
        (void*)&x, (void*)&ei,
        (void*)&Wl0, (void*)&Wr0, (void*)&b0,
        (void*)&Wl1, (void*)&Wr1, (void*)&b1,
        (void*)&Wl2, (void*)&Wr2, (void*)&b2,
        (void*)&cnt, (void*)&rowstart, (void*)&cursor, (void*)&bsum, (void*)&csr_src,
        (void*)&pk0, (void*)&pk1, (void*)&pkz,
        (void*)&x_bf, (void*)&h_bf, (void*)&z_bf, (void*)&r_f32,
        (void*)&out
    };
    hipError_t err = hipLaunchCooperativeKernel((void*)sage_all, dim3(GRID_ALL),
                                                dim3(256), kargs, 0, stream);
    if (err == hipSuccess) return;

    // ---- fallback: proven R9 multi-kernel pipeline ----
    hipMemsetAsync(cnt, 0, N_NODES * sizeof(int), stream);
    prep<<<7594, 256, 0, stream>>>(ei, cnt, x, x_bf,
                                   Wl0, Wr0, Wl1, Wr1, Wl2, Wr2, pk0, pk1, pkz);
    block_sums<<<SCAN_BLOCKS, 256, 0, stream>>>(cnt, bsum);
    apply_scan2<<<SCAN_BLOCKS, 256, 0, stream>>>(cnt, bsum, rowstart, cursor);
    fill_csr_mp<<<1024, 256, 0, stream>>>(ei, cursor, csr_src);
    sage_fused_k<false><<<782, 256, 0, stream>>>(x_bf, rowstart, csr_src, pk0, b0,
                                                 nullptr, nullptr, h_bf, nullptr, nullptr);
    sage_fused_k<true><<<782, 256, 0, stream>>>(h_bf, rowstart, csr_src, pk1, b1,
                                                pkz, b2, nullptr, z_bf, r_f32);
    final_agg_softmax2<<<1563, 256, 0, stream>>>(z_bf, r_f32, rowstart, csr_src, out);
}

// Round 11
// 273.897 us; speedup vs baseline: 3.4326x; 3.4326x over previous
//
#include <hip/hip_runtime.h>

#define N_NODES 50000
#define N_EDGES 800000
#define SCAN_BLOCKS 196          // ceil(50000/256)
#define WIN 6250                 // dst window per XCD group (50000/8)

typedef __attribute__((ext_vector_type(8))) short short8;
typedef __attribute__((ext_vector_type(4))) float f32x4;
typedef unsigned short ushort_t;
typedef unsigned int uint_t;

// ---------------- helpers ----------------
__device__ inline ushort_t f2bf(float f) {
    union { float f; uint_t u; } v; v.f = f;
    uint_t u = v.u;
    u += 0x7fffu + ((u >> 16) & 1u);   // RNE
    return (ushort_t)(u >> 16);
}
__device__ inline float bflo(uint_t v) { return __uint_as_float(v << 16); }
__device__ inline float bfhi(uint_t v) { return __uint_as_float(v & 0xffff0000u); }

#define ACC8(V) { a[0] += bflo((V).x); a[1] += bfhi((V).x); \
                  a[2] += bflo((V).y); a[3] += bfhi((V).y); \
                  a[4] += bflo((V).z); a[5] += bfhi((V).z); \
                  a[6] += bflo((V).w); a[7] += bfhi((V).w); }

// ---------------- fused prep: edge count + fp32->bf16 cvt + weight packs ----------------
// blocks 0..1023: XCD-windowed dst counting (blockIdx&7 -> XCD role; int4 edge reads)
// blocks 1024..7273: x -> bf16 (row-major [50000][128])
// blocks 7274..7593: pack all 3 layer B-fragments
__global__ void prep(const int* __restrict__ ei, int* __restrict__ cnt,
                     const float* __restrict__ x, ushort_t* __restrict__ x_bf,
                     const float* __restrict__ Wl0, const float* __restrict__ Wr0,
                     const float* __restrict__ Wl1, const float* __restrict__ Wr1,
                     const float* __restrict__ Wl2, const float* __restrict__ Wr2,
                     ushort_t* __restrict__ pk0, ushort_t* __restrict__ pk1,
                     ushort_t* __restrict__ pkz) {
    int b = blockIdx.x;
    if (b < 1024) {
        int g = b & 7;
        int bi = b >> 3;
        int lo = g * WIN;
        const int4* dv = (const int4*)(ei + N_EDGES);
        for (int q = bi * 256 + threadIdx.x; q < N_EDGES / 4; q += 128 * 256) {
            int4 d = dv[q];
            if ((unsigned)(d.x - lo) < WIN) atomicAdd(&cnt[d.x], 1);
            if ((unsigned)(d.y - lo) < WIN) atomicAdd(&cnt[d.y], 1);
            if ((unsigned)(d.z - lo) < WIN) atomicAdd(&cnt[d.z], 1);
            if ((unsigned)(d.w - lo) < WIN) atomicAdd(&cnt[d.w], 1);
        }
    } else if (b < 7274) {
        int i = (b - 1024) * 256 + threadIdx.x;
        if (i < 1600000) {
            float4 v = ((const float4*)x)[i];
            ushort4 o;
            o.x = f2bf(v.x); o.y = f2bf(v.y); o.z = f2bf(v.z); o.w = f2bf(v.w);
            ((ushort4*)x_bf)[i] = o;
        }
    } else {
        int gi = (b - 7274) * 256 + threadIdx.x;    // 81920 total
        const float* Wl; const float* Wr; ushort_t* dst; int idx; bool zr = false;
        if (gi < 32768)       { Wl = Wl0; Wr = Wr0; dst = pk0; idx = gi; }
        else if (gi < 65536)  { Wl = Wl1; Wr = Wr1; dst = pk1; idx = gi - 32768; }
        else if (gi < 81920)  { Wl = Wl2; Wr = Wr2; dst = pkz; idx = gi - 65536; zr = true; }
        else return;
        int j = idx & 7, l = (idx >> 3) & 63, t = (idx >> 9) & 7, ks = idx >> 12;
        int n = t * 16 + (l & 15);
        int k = ks * 32 + (l >> 4) * 8 + j;
        float w;
        if (zr) w = (n < 64) ? Wl[k * 64 + n] : Wr[k * 64 + (n - 64)];
        else    w = (k < 128) ? Wl[k * 128 + n] : Wr[(k - 128) * 128 + n];
        dst[idx] = f2bf(w);
    }
}

// ---------------- CSR build (scan chain + fill; int4 edge reads) ----------------
__global__ void fill_csr_mp(const int* __restrict__ ei, int* __restrict__ cursor,
                            int* __restrict__ csr_src) {
    int g = blockIdx.x & 7;
    int nb = gridDim.x >> 3;
    int bi = blockIdx.x >> 3;
    int lo = g * WIN;
    const int4* dv = (const int4*)(ei + N_EDGES);
    const int4* sv = (const int4*)ei;
    for (int q = bi * 256 + threadIdx.x; q < N_EDGES / 4; q += nb * 256) {
        int4 d = dv[q];
        bool m0 = (unsigned)(d.x - lo) < WIN;
        bool m1 = (unsigned)(d.y - lo) < WIN;
        bool m2 = (unsigned)(d.z - lo) < WIN;
        bool m3 = (unsigned)(d.w - lo) < WIN;
        if (m0 | m1 | m2 | m3) {
            int4 s = sv[q];
            if (m0) { int p = atomicAdd(&cursor[d.x], 1); csr_src[p] = s.x; }
            if (m1) { int p = atomicAdd(&cursor[d.y], 1); csr_src[p] = s.y; }
            if (m2) { int p = atomicAdd(&cursor[d.z], 1); csr_src[p] = s.z; }
            if (m3) { int p = atomicAdd(&cursor[d.w], 1); csr_src[p] = s.w; }
        }
    }
}

__global__ void block_sums(const int* __restrict__ cnt, int* __restrict__ bsum) {
    int i = blockIdx.x * 256 + threadIdx.x;
    int v = (i < N_NODES) ? cnt[i] : 0;
    for (int off = 32; off; off >>= 1) v += __shfl_down(v, off, 64);
    __shared__ int s[4];
    if ((threadIdx.x & 63) == 0) s[threadIdx.x >> 6] = v;
    __syncthreads();
    if (threadIdx.x == 0) bsum[blockIdx.x] = s[0] + s[1] + s[2] + s[3];
}

// merged scan: per-block scan of its cnt chunk AND in-kernel scan of bsum
__global__ void apply_scan2(const int* __restrict__ cnt, const int* __restrict__ bsum,
                            int* __restrict__ rowstart, int* __restrict__ cursor) {
    __shared__ int s[256];
    __shared__ int p[256];
    int t = threadIdx.x;
    int i = blockIdx.x * 256 + t;
    int v = (i < N_NODES) ? cnt[i] : 0;
    int bv = (t < SCAN_BLOCKS) ? bsum[t] : 0;
    s[t] = v;
    p[t] = bv;
    __syncthreads();
    for (int off = 1; off < 256; off <<= 1) {
        int as_ = (t >= off) ? s[t - off] : 0;
        int ap_ = (t >= off) ? p[t - off] : 0;
        __syncthreads();
        s[t] += as_;
        p[t] += ap_;
        __syncthreads();
    }
    int bprefix = (blockIdx.x > 0) ? p[blockIdx.x - 1] : 0;
    int excl = s[t] - v + bprefix;
    if (i < N_NODES) { rowstart[i] = excl; cursor[i] = excl; }
    if (blockIdx.x == 0 && t == 0) rowstart[N_NODES] = N_EDGES;
}

// ---------------- fused layer: mean-aggregate -> LDS -> MFMA GEMM (-> optional 2nd GEMM) ----------------
// Proven structure (R1/R6/R9, 46.6us): block = 4 waves, 64 nodes; aggregation
// gathers four 256B rows per wave instruction (16 lanes x dwordx4); mean tile
// in LDS (stride 68 uints); GEMM-1 computes h = relu([mean|root]@[Wl;Wr]+b).
// Gathers use NORMAL (L1-allocating) loads: R8 proved NT loads cost +24%.
// ZR=true (layer 1): h2 tile stays in LDS and a second MFMA pass computes
// [z|r] = h2 @ [Wl2|Wr2] (+b2 on r) directly.
template <bool ZR>
__global__ __launch_bounds__(256) void sage_fused_k(
    const ushort_t* __restrict__ feat_bf,
    const int* __restrict__ rowstart,
    const int* __restrict__ csr_src,
    const ushort_t* __restrict__ Bpk, const float* __restrict__ bias,
    const ushort_t* __restrict__ Bz, const float* __restrict__ bias2,
    ushort_t* __restrict__ out_bf,
    ushort_t* __restrict__ z_bf, float* __restrict__ r_f32) {
    __shared__ uint_t mlds[64][68];
    int lane = threadIdx.x & 63;
    int wave = threadIdx.x >> 6;
    int rowBase = blockIdx.x * 64 + wave * 16;
    int sub = lane >> 4;                  // node slot within wave pass
    int sl  = lane & 15;                  // lane within node row
    int gb  = sub << 4;
    const uint_t* base = (const uint_t*)feat_bf;

    for (int p = 0; p < 4; ++p) {
        int node = rowBase + p * 4 + sub;
        int s0 = 0, s1 = 0;
        if (node < N_NODES) { s0 = rowstart[node]; s1 = rowstart[node + 1]; }
        float a[8];
        #pragma unroll
        for (int k = 0; k < 8; ++k) a[k] = 0.f;

        int pos = s0;
        while (__any(pos < s1)) {
            int m = min(16, s1 - pos);               // group-uniform, may be <=0
            int idxr = (sl < m) ? csr_src[pos + sl] : 0;
            int mm = max(m, 0);
            mm = max(mm, __shfl_xor(mm, 16, 64));
            mm = max(mm, __shfl_xor(mm, 32, 64));
            for (int j = 0; j < mm; j += 8) {
                int  sidx[8];
                bool vld[8];
                #pragma unroll
                for (int k = 0; k < 8; ++k) {
                    int q = __shfl(idxr, (gb + j + k) & 63, 64);
                    vld[k]  = (j + k < m);
                    sidx[k] = vld[k] ? q : 0;        // safe clamped addr, result discarded
                }
                uint4 V[8];
                #pragma unroll
                for (int k = 0; k < 8; ++k)
                    V[k] = *(const uint4*)(base + (size_t)sidx[k] * 64 + (sl << 2));
                #pragma unroll
                for (int k = 0; k < 8; ++k)
                    if (vld[k]) { ACC8(V[k]); }
            }
            pos += 16;
        }
        float inv = 1.0f / fmaxf((float)(s1 - s0), 1.0f);
        uint4 o;
        o.x = (uint_t)f2bf(a[0] * inv) | ((uint_t)f2bf(a[1] * inv) << 16);
        o.y = (uint_t)f2bf(a[2] * inv) | ((uint_t)f2bf(a[3] * inv) << 16);
        o.z = (uint_t)f2bf(a[4] * inv) | ((uint_t)f2bf(a[5] * inv) << 16);
        o.w = (uint_t)f2bf(a[6] * inv) | ((uint_t)f2bf(a[7] * inv) << 16);
        *((uint4*)&mlds[wave * 16 + p * 4 + sub][sl << 2]) = o;
    }
    __syncthreads();

    // ---- GEMM-1: A = [mean(LDS) | root(global)], B pre-packed ----
    int row16 = lane & 15;
    int quad  = lane >> 4;
    int arow  = min(rowBase + row16, N_NODES - 1);
    const ushort_t* rrow = feat_bf + (size_t)arow * 128;
    const short8* bp = (const short8*)Bpk + lane;

    f32x4 acc[8];
    #pragma unroll
    for (int t = 0; t < 8; ++t) { f32x4 z = {0.f, 0.f, 0.f, 0.f}; acc[t] = z; }

    #pragma unroll
    for (int ks = 0; ks < 8; ++ks) {
        short8 afrag;
        if (ks < 4)
            afrag = *(const short8*)&mlds[wave * 16 + row16][ks * 16 + quad * 4];
        else
            afrag = *(const short8*)(rrow + (ks - 4) * 32 + quad * 8);
        #pragma unroll
        for (int t = 0; t < 8; ++t) {
            short8 bfrag = bp[(ks * 8 + t) * 64];
            acc[t] = __builtin_amdgcn_mfma_f32_16x16x32_bf16(afrag, bfrag, acc[t], 0, 0, 0);
        }
    }

    if (!ZR) {
        #pragma unroll
        for (int t = 0; t < 8; ++t) {
            int col = t * 16 + row16;
            float bv = bias[col];
            #pragma unroll
            for (int r = 0; r < 4; ++r) {
                int row = rowBase + quad * 4 + r;
                if (row < N_NODES) {
                    float v = fmaxf(acc[t][r] + bv, 0.f);
                    out_bf[(size_t)row * 128 + col] = f2bf(v);
                }
            }
        }
    } else {
        // h2 tile -> LDS (reuse mean tile; all rows wave-local, mean already consumed)
        #pragma unroll
        for (int t = 0; t < 8; ++t) {
            int col = t * 16 + row16;
            float bv = bias[col];
            #pragma unroll
            for (int r = 0; r < 4; ++r) {
                float v = fmaxf(acc[t][r] + bv, 0.f);
                ((ushort_t*)&mlds[wave * 16 + quad * 4 + r][0])[col] = f2bf(v);
            }
        }
        __syncthreads();

        // ---- GEMM-2: [z | r] = h2(LDS) @ [Wl2 | Wr2] ----
        const short8* bz = (const short8*)Bz + lane;
        f32x4 acc2[8];
        #pragma unroll
        for (int t = 0; t < 8; ++t) { f32x4 z = {0.f, 0.f, 0.f, 0.f}; acc2[t] = z; }

        #pragma unroll
        for (int ks = 0; ks < 4; ++ks) {
            short8 afrag = *(const short8*)((const ushort_t*)&mlds[wave * 16 + row16][0]
                                            + ks * 32 + quad * 8);
            #pragma unroll
            for (int t = 0; t < 8; ++t) {
                short8 bfrag = bz[(ks * 8 + t) * 64];
                acc2[t] = __builtin_amdgcn_mfma_f32_16x16x32_bf16(afrag, bfrag, acc2[t], 0, 0, 0);
            }
        }

        #pragma unroll
        for (int t = 0; t < 8; ++t) {
            int col = t * 16 + row16;
            #pragma unroll
            for (int r = 0; r < 4; ++r) {
                int row = rowBase + quad * 4 + r;
                if (row < N_NODES) {
                    if (col < 64) {
                        z_bf[(size_t)row * 64 + col] = f2bf(acc2[t][r]);
                    } else {
                        r_f32[(size_t)row * 64 + (col - 64)] = acc2[t][r] + bias2[col - 64];
                    }
                }
            }
        }
    }
}

// ---------------- final: mean(z[src]) + r, log_softmax (8 rows/instr gather) ----------------
__global__ __launch_bounds__(256) void final_agg_softmax2(
    const ushort_t* __restrict__ z_bf, const float* __restrict__ r_f32,
    const int* __restrict__ rowstart, const int* __restrict__ csr_src,
    float* __restrict__ out) {
    int lane = threadIdx.x & 63;
    int wave = threadIdx.x >> 6;
    int sub = lane >> 3;                  // node slot 0..7
    int sl  = lane & 7;                   // lane within node row
    int gb  = sub << 3;
    int node = blockIdx.x * 32 + wave * 8 + sub;
    int s0 = 0, s1 = 0;
    if (node < N_NODES) { s0 = rowstart[node]; s1 = rowstart[node + 1]; }

    float a[8];
    #pragma unroll
    for (int k = 0; k < 8; ++k) a[k] = 0.f;
    const uint_t* zb = (const uint_t*)z_bf;

    int pos = s0;
    while (__any(pos < s1)) {
        int m = min(8, s1 - pos);
        int idxr = (sl < m) ? csr_src[pos + sl] : 0;
        int  sidx[8];
        bool vld[8];
        #pragma unroll
        for (int k = 0; k < 8; ++k) {
            int q = __shfl(idxr, (gb + k) & 63, 64);
            vld[k]  = (k < m);
            sidx[k] = vld[k] ? q : 0;
        }
        uint4 V[8];
        #pragma unroll
        for (int k = 0; k < 8; ++k)
            V[k] = *(const uint4*)(zb + (size_t)sidx[k] * 32 + (sl << 2));
        #pragma unroll
        for (int k = 0; k < 8; ++k)
            if (vld[k]) { ACC8(V[k]); }
        pos += 8;
    }
    if (node >= N_NODES) return;

    float inv = 1.0f / fmaxf((float)(s1 - s0), 1.0f);
    const float4* rr = (const float4*)(r_f32 + (size_t)node * 64 + sl * 8);
    float4 rA = rr[0], rB = rr[1];
    float h[8];
    h[0] = a[0] * inv + rA.x; h[1] = a[1] * inv + rA.y;
    h[2] = a[2] * inv + rA.z; h[3] = a[3] * inv + rA.w;
    h[4] = a[4] * inv + rB.x; h[5] = a[5] * inv + rB.y;
    h[6] = a[6] * inv + rB.z; h[7] = a[7] * inv + rB.w;

    float mx = fmaxf(fmaxf(fmaxf(h[0], h[1]), fmaxf(h[2], h[3])),
                     fmaxf(fmaxf(h[4], h[5]), fmaxf(h[6], h[7])));
    mx = fmaxf(mx, __shfl_xor(mx, 1, 64));
    mx = fmaxf(mx, __shfl_xor(mx, 2, 64));
    mx = fmaxf(mx, __shfl_xor(mx, 4, 64));
    float s = 0.f;
    #pragma unroll
    for (int k = 0; k < 8; ++k) s += expf(h[k] - mx);
    s += __shfl_xor(s, 1, 64);
    s += __shfl_xor(s, 2, 64);
    s += __shfl_xor(s, 4, 64);
    float lse = mx + logf(s);

    size_t o1 = (size_t)node * 64 + sl * 8;
    size_t o2 = (size_t)N_NODES * 64 + o1;
    *(float4*)(out + o1)     = make_float4(h[0] - lse, h[1] - lse, h[2] - lse, h[3] - lse);
    *(float4*)(out + o1 + 4) = make_float4(h[4] - lse, h[5] - lse, h[6] - lse, h[7] - lse);
    *(float4*)(out + o2)     = make_float4(h[0], h[1], h[2], h[3]);
    *(float4*)(out + o2 + 4) = make_float4(h[4], h[5], h[6], h[7]);
}

extern "C" void kernel_launch(void* const* d_in, const int* in_sizes, int n_in,
                              void* d_out, int out_size, void* d_ws, size_t ws_size,
                              hipStream_t stream) {
    const float* x  = (const float*)d_in[0];
    const int* ei   = (const int*)d_in[1];
    const float* Wl0 = (const float*)d_in[2];
    const float* Wr0 = (const float*)d_in[3];
    const float* b0  = (const float*)d_in[4];
    const float* Wl1 = (const float*)d_in[5];
    const float* Wr1 = (const float*)d_in[6];
    const float* b1  = (const float*)d_in[7];
    const float* Wl2 = (const float*)d_in[8];
    const float* Wr2 = (const float*)d_in[9];
    const float* b2  = (const float*)d_in[10];
    float* out = (float*)d_out;

    char* ws = (char*)d_ws;
    int* cnt      = (int*)(ws + 0x000000);
    int* rowstart = (int*)(ws + 0x040000);
    int* cursor   = (int*)(ws + 0x080000);
    int* bsum     = (int*)(ws + 0x0C0000);
    int* csr_src  = (int*)(ws + 0x100000);            // 3.2 MB
    ushort_t* pk0 = (ushort_t*)(ws + 0x420000);       // 64 KB
    ushort_t* pk1 = (ushort_t*)(ws + 0x440000);       // 64 KB
    ushort_t* pkz = (ushort_t*)(ws + 0x460000);       // 32 KB
    ushort_t* x_bf = (ushort_t*)(ws + 0x0500000);     // 12.8 MB [50000][128]
    ushort_t* h_bf = (ushort_t*)(ws + 0x1200000);     // 12.8 MB [50000][128]
    ushort_t* z_bf = (ushort_t*)(ws + 0x1F00000);     // 6.4 MB  [50000][64]
    float*    r_f32 = (float*)  (ws + 0x2600000);     // 12.8 MB [50000][64]

    // ---- prep: edge counting + x->bf16 + all weight packs (1 launch) ----
    hipMemsetAsync(cnt, 0, N_NODES * sizeof(int), stream);
    prep<<<7594, 256, 0, stream>>>(ei, cnt, x, x_bf,
                                   Wl0, Wr0, Wl1, Wr1, Wl2, Wr2, pk0, pk1, pkz);

    // ---- CSR scan + fill (merged scan: 2 kernels) ----
    block_sums<<<SCAN_BLOCKS, 256, 0, stream>>>(cnt, bsum);
    apply_scan2<<<SCAN_BLOCKS, 256, 0, stream>>>(cnt, bsum, rowstart, cursor);
    fill_csr_mp<<<1024, 256, 0, stream>>>(ei, cursor, csr_src);

    // ---- layer 0 (fused aggregate + GEMM): x_bf -> h_bf ----
    sage_fused_k<false><<<782, 256, 0, stream>>>(x_bf, rowstart, csr_src, pk0, b0,
                                                 nullptr, nullptr, h_bf, nullptr, nullptr);

    // ---- layer 1 + layer-2 transform fused: h_bf -> (z_bf, r_f32); h2 stays in LDS ----
    sage_fused_k<true><<<782, 256, 0, stream>>>(h_bf, rowstart, csr_src, pk1, b1,
                                                pkz, b2, nullptr, z_bf, r_f32);

    // ---- final: gather z + residual + log_softmax ----
    final_agg_softmax2<<<1563, 256, 0, stream>>>(z_bf, r_f32, rowstart, csr_src, out);
}